// Round 5
// baseline (151.546 us; speedup 1.0000x reference)
//
#include <hip/hip_runtime.h>
#include <stdint.h>

// OrthogonalLinear: pyramid Givens circuit, n = m = 512, B = 256.
// T = 1021 layers; layer t has gates (i, i+1) for i = (t&1), (t&1)+2, ...,
// i <= min(t, 1020-t). Sequential gate order: k = 1..511, i = k-1 down to 0;
// theta index is sequential in that order; t = 2(k-1) - i.
//
// Table W4 (d_ws), float4 units: pair p (layers t=2p, 2p+1) occupies
// float4 [p*256, (p+1)*256). Quarter q in 0..3, lane L: idx = p*256 + q*64 + L:
//   q0 = (cE0,sE0,cE1,sE1)  even gates at wires 8L+0, 8L+2
//   q1 = (cE2,sE2,cE3,sE3)  even gates at wires 8L+4, 8L+6
//   q2 = (cO0,sO0,cO1,sO1)  odd  gates at wires 8L+1, 8L+3
//   q3 = (cO2,sO2,cO3,sO3)  odd  gates at wires 8L+5, 8L+7
// Matches global_load_lds lane mapping (base + lane*16) so consumer
// ds_read_b128 at lane*16 is conflict-free. "Pair" 510 = final layer t=1020
// (only q0/q1 are read; gate i=0 is the only live gate). Total 130688 float4.

#define N_WIRES 512
#define BATCH   256
#define PAIRS   510
#define CHUNK   6                    // pairs per chunk; 510 = 6 * 85
#define NCHUNK  85
#define CHUNK4  (CHUNK * 256)        // 1536 float4 = 24 KB per chunk
#define LOADS_PER_CHUNK (CHUNK * 4)  // 24 global_load_lds per chunk
#define FINAL4  (PAIRS * 256)        // 130560
#define TOTAL4  (FINAL4 + 128)       // 130688
#define N_THETAS 130816

// ---------------- kernel 1a: fill table with identity (c=1, s=0) -----------
__global__ __launch_bounds__(256) void fill_kernel(float4* __restrict__ W4) {
  int tid = blockIdx.x * 256 + threadIdx.x;
  if (tid < TOTAL4) W4[tid] = make_float4(1.0f, 0.0f, 1.0f, 0.0f);
}

// ---------------- kernel 1b: scatter cos/sin, coalesced theta loads --------
__global__ __launch_bounds__(256) void scatter_kernel(
    const float* __restrict__ thetas, float2* __restrict__ W2) {
  int tid = blockIdx.x * 256 + threadIdx.x;
  if (tid >= N_THETAS) return;
  // recover k: k(k-1)/2 <= tid < k(k+1)/2
  int k = (int)((1.0 + sqrt((double)(8 * tid + 1))) * 0.5);
  int base = (k * (k - 1)) >> 1;
  if (base > tid) { --k; base -= k; }
  else { int nb = base + k; if (nb <= tid) { base = nb; ++k; } }
  int j = tid - base;        // 0..k-1
  int i = k - 1 - j;         // wire
  int t = k - 1 + j;         // layer, 0..1020
  float c, s;
  __sincosf(thetas[tid], &s, &c);
  int p = t >> 1;            // t=1020 -> p=510 = final block (q=0, L=0)
  int L = i >> 3;
  int g = (i >> 1) & 3;
  int q = ((t & 1) ? 2 : 0) + (g >> 1);
  int elem = g & 1;
  W2[(p * 256 + q * 64 + L) * 2 + elem] = make_float2(c, s);
}

// ---------------- kernel 2: apply circuit, wave per row ----------------
__device__ __forceinline__ float dpp_shr1(float v) {  // lane i <- lane i-1; lane0 <- 0
  return __int_as_float(__builtin_amdgcn_update_dpp(
      0, __float_as_int(v), 0x138, 0xF, 0xF, true));  // wave_shr:1
}
__device__ __forceinline__ float dpp_shl1(float v) {  // lane i <- lane i+1; lane63 <- 0
  return __int_as_float(__builtin_amdgcn_update_dpp(
      0, __float_as_int(v), 0x130, 0xF, 0xF, true));  // wave_shl:1
}

__device__ __forceinline__ void gate(float& a, float& b, float c, float s) {
  float na = fmaf(c, a, s * b);
  float nb = fmaf(c, b, -(s * a));
  a = na;
  b = nb;
}

__device__ __forceinline__ void even_layer(float (&v)[8], float4 q0, float4 q1) {
  gate(v[0], v[1], q0.x, q0.y);
  gate(v[2], v[3], q0.z, q0.w);
  gate(v[4], v[5], q1.x, q1.y);
  gate(v[6], v[7], q1.z, q1.w);
}

__device__ __forceinline__ void odd_layer(float (&v)[8], float4 q2, float4 q3,
                                          int lane) {
  // cl/sl depend only on q3 (LDS) -> off the state-dependent critical path.
  float cl = dpp_shr1(q3.z);
  float sl = dpp_shr1(q3.w);            // lane0 -> 0 (correct: no gate below 0)
  cl = (lane == 0) ? 1.0f : cl;         // lane0 boundary gate is identity
  float rv0 = dpp_shl1(v[0]);           // right neighbor's wire 8L+8 (post-even)
  float lv7 = dpp_shr1(v[7]);           // left neighbor's wire 8L-1 (post-even)
  gate(v[1], v[2], q2.x, q2.y);
  gate(v[3], v[4], q2.z, q2.w);
  gate(v[5], v[6], q3.x, q3.y);
  // lane63: q3.z=1, q3.w=0 always (gate i=511 never live) -> nv7 = v7, rv0 dead.
  float nv7 = fmaf(q3.z, v[7], q3.w * rv0);  // a-side of gate (8L+7, 8L+8)
  float nv0 = fmaf(cl, v[0], -(sl * lv7));   // b-side of gate (8L-1, 8L)
  v[7] = nv7;
  v[0] = nv0;
}

__device__ __forceinline__ void issue_chunk(const float4* __restrict__ Wg,
                                            float4* lds_base, int c, int bsel,
                                            int lane) {
  const float4* src = Wg + c * CHUNK4 + lane;  // per-lane global addr
  float4* dst = lds_base + bsel * CHUNK4;      // wave-uniform LDS base
#pragma unroll
  for (int q = 0; q < LOADS_PER_CHUNK; ++q) {
    __builtin_amdgcn_global_load_lds(
        (__attribute__((address_space(1))) uint32_t*)(src + q * 64),
        (__attribute__((address_space(3))) uint32_t*)(dst + q * 64),
        16, 0, 0);
  }
}

__global__ __launch_bounds__(64, 1) void circuit_kernel(
    const float* __restrict__ x, const float* __restrict__ W,
    const float* __restrict__ bias, float* __restrict__ out) {
  __shared__ float4 lds[3 * CHUNK4];   // 73728 B, triple-buffered
  const int lane = threadIdx.x;
  const int row = blockIdx.x;
  const float4* __restrict__ Wg = (const float4*)W;

  const float* xr = x + row * N_WIRES + lane * 8;
  float4 x0 = *(const float4*)(xr);
  float4 x1 = *(const float4*)(xr + 4);
  float v[8] = {x0.x, x0.y, x0.z, x0.w, x1.x, x1.y, x1.z, x1.w};

  // DMA pipeline, depth 3: while computing chunk k, k+1 and k+2 are in flight;
  // chunk k+3 is issued after k's compute (into k's buffer).
  issue_chunk(Wg, lds, 0, 0, lane);
  issue_chunk(Wg, lds, 1, 1, lane);
  issue_chunk(Wg, lds, 2, 2, lane);

  int bsel = 0;
  for (int k = 0; k < NCHUNK; ++k) {
    if (k + 2 < NCHUNK) {
      asm volatile("s_waitcnt vmcnt(48)" ::: "memory");   // chunk k landed
    } else if (k + 1 < NCHUNK) {
      asm volatile("s_waitcnt vmcnt(24)" ::: "memory");
    } else {
      asm volatile("s_waitcnt vmcnt(0)" ::: "memory");
    }
    const float4* buf = lds + bsel * CHUNK4;
#pragma unroll
    for (int pr = 0; pr < CHUNK; ++pr) {
      float4 q0 = buf[(pr * 4 + 0) * 64 + lane];
      float4 q1 = buf[(pr * 4 + 1) * 64 + lane];
      float4 q2 = buf[(pr * 4 + 2) * 64 + lane];
      float4 q3 = buf[(pr * 4 + 3) * 64 + lane];
      even_layer(v, q0, q1);
      odd_layer(v, q2, q3, lane);
    }
    if (k + 3 < NCHUNK) issue_chunk(Wg, lds, k + 3, bsel, lane);
    bsel = (bsel == 2) ? 0 : bsel + 1;
  }

  // final even layer t = 1020 (table pre-masked to identity except gate 0)
  float4 f0 = Wg[FINAL4 + lane];        // q=0
  float4 f1 = Wg[FINAL4 + 64 + lane];   // q=1
  even_layer(v, f0, f1);

  const float* br = bias + lane * 8;
  float4 b0 = *(const float4*)(br);
  float4 b1 = *(const float4*)(br + 4);
  float4 o0 = {v[0] + b0.x, v[1] + b0.y, v[2] + b0.z, v[3] + b0.w};
  float4 o1 = {v[4] + b1.x, v[5] + b1.y, v[6] + b1.z, v[7] + b1.w};
  float* orow = out + row * N_WIRES + lane * 8;
  *(float4*)(orow) = o0;
  *(float4*)(orow + 4) = o1;
}

extern "C" void kernel_launch(void* const* d_in, const int* in_sizes, int n_in,
                              void* d_out, int out_size, void* d_ws,
                              size_t ws_size, hipStream_t stream) {
  const float* x = (const float*)d_in[0];       // (256, 512) f32
  const float* thetas = (const float*)d_in[1];  // (130816,) f32
  const float* bias = (const float*)d_in[2];    // (512,) f32
  float* out = (float*)d_out;                   // (256, 512) f32

  float* W = (float*)d_ws;                      // 130688 float4 = 2.09 MB

  fill_kernel<<<(TOTAL4 + 255) / 256, 256, 0, stream>>>((float4*)W);
  scatter_kernel<<<(N_THETAS + 255) / 256, 256, 0, stream>>>(thetas, (float2*)W);
  circuit_kernel<<<BATCH, 64, 0, stream>>>(x, W, bias, out);
}

// Round 6
// 133.768 us; speedup vs baseline: 1.1329x; 1.1329x over previous
//
#include <hip/hip_runtime.h>
#include <stdint.h>

// OrthogonalLinear: pyramid Givens circuit, n = m = 512, B = 256.
// T = 1021 layers; layer t has gates (i, i+1) for i = (t&1), (t&1)+2, ...,
// i <= min(t, 1020-t). theta index: k = (t+i)/2 + 1, idx = k(k-1)/2 + (k-1-i).
//
// Table W4 (d_ws), float4 units: pair p (layers t=2p, 2p+1) occupies
// float4 [p*256, (p+1)*256). Quarter q in 0..3, lane L: idx = p*256 + q*64 + L:
//   q0 = (cE0,sE0,cE1,sE1)  even gates at wires 8L+0, 8L+2
//   q1 = (cE2,sE2,cE3,sE3)  even gates at wires 8L+4, 8L+6
//   q2 = (cO0,sO0,cO1,sO1)  odd  gates at wires 8L+1, 8L+3
//   q3 = (cO2,sO2,cO3,sO3)  odd  gates at wires 8L+5, 8L+7
// Block p=510 (128 float4, q=0/1 only) is the final even layer t=1020.
// Dead slots hold identity (1,0). Total 130688 float4 = 2.09 MB.
//
// circuit_kernel (R6): NO LDS. Register ring of PF=6 pairs (96 VGPRs),
// 4 global_load_dwordx4 per pair, with an asm-volatile s_waitcnt vmcnt(20)
// memory barrier per pair: loads cannot be sunk across it, so prefetch
// distance is structurally 5 pairs (~450 cyc of compute) > L2 latency.
// Max outstanding = 26 < 63 (vmcnt cap). Cross-lane via DPP (VALU-only).

#define N_WIRES 512
#define BATCH   256
#define PAIRS   510
#define PF      6                  // ring depth (pairs); 510 = 6 * 85
#define FINAL4  (PAIRS * 256)      // 130560
#define TOTAL4  (FINAL4 + 128)     // 130688
#define TOTAL2  (TOTAL4 * 2)      // 261376 float2 slots

// ---------------- kernel 1: build table, one float2 store per thread -------
__global__ __launch_bounds__(256) void sincos_kernel(
    const float* __restrict__ thetas, float2* __restrict__ W2) {
  int tid = blockIdx.x * 256 + threadIdx.x;
  if (tid >= TOTAL2) return;
  int p = tid >> 9;            // pair-block (512 float2 each); p=510 = final
  int r = tid & 511;
  int q = r >> 7;              // quarter 0..3
  int L = (r >> 1) & 63;       // lane
  int e = r & 1;               // gate within quarter-half
  int h = q >> 1;              // 0 = even layer, 1 = odd layer
  int t = 2 * p + h;
  int i = 8 * L + 4 * (q & 1) + 2 * e + h;   // wire of gate (i, i+1)
  float c = 1.0f, s = 0.0f;
  if (i <= min(t, 1020 - t)) {
    int k = ((t + i) >> 1) + 1;
    int idx = ((k * (k - 1)) >> 1) + (k - 1 - i);
    __sincosf(thetas[idx], &s, &c);
  }
  W2[tid] = make_float2(c, s);
}

// ---------------- kernel 2: apply circuit, wave per row ----------------
__device__ __forceinline__ float dpp_shr1(float v) {  // lane i <- i-1; lane0 <- 0
  return __int_as_float(__builtin_amdgcn_update_dpp(
      0, __float_as_int(v), 0x138, 0xF, 0xF, true));  // wave_shr:1
}
__device__ __forceinline__ float dpp_shl1(float v) {  // lane i <- i+1; lane63 <- 0
  return __int_as_float(__builtin_amdgcn_update_dpp(
      0, __float_as_int(v), 0x130, 0xF, 0xF, true));  // wave_shl:1
}

__device__ __forceinline__ void gate(float& a, float& b, float c, float s) {
  float na = fmaf(c, a, s * b);
  float nb = fmaf(c, b, -(s * a));
  a = na;
  b = nb;
}

__device__ __forceinline__ void even_layer(float (&v)[8], float4 q0, float4 q1) {
  gate(v[0], v[1], q0.x, q0.y);
  gate(v[2], v[3], q0.z, q0.w);
  gate(v[4], v[5], q1.x, q1.y);
  gate(v[6], v[7], q1.z, q1.w);
}

__device__ __forceinline__ void odd_layer(float (&v)[8], float4 q2, float4 q3,
                                          int lane) {
  float cl = dpp_shr1(q3.z);            // left neighbor's boundary gate c
  float sl = dpp_shr1(q3.w);            // lane0 -> 0 (no gate below wire 0)
  cl = (lane == 0) ? 1.0f : cl;
  float rv0 = dpp_shl1(v[0]);           // right neighbor's wire 8L+8 (post-even)
  float lv7 = dpp_shr1(v[7]);           // left neighbor's wire 8L-1 (post-even)
  gate(v[1], v[2], q2.x, q2.y);
  gate(v[3], v[4], q2.z, q2.w);
  gate(v[5], v[6], q3.x, q3.y);
  // lane63: q3.z=1, q3.w=0 (gate i=511 never live) -> nv7 = v[7], rv0 dead.
  float nv7 = fmaf(q3.z, v[7], q3.w * rv0);  // a-side of gate (8L+7, 8L+8)
  float nv0 = fmaf(cl, v[0], -(sl * lv7));   // b-side of gate (8L-1, 8L)
  v[7] = nv7;
  v[0] = nv0;
}

__global__ __launch_bounds__(64, 1) void circuit_kernel(
    const float* __restrict__ x, const float* __restrict__ W,
    const float* __restrict__ bias, float* __restrict__ out) {
  const int lane = threadIdx.x;
  const int row = blockIdx.x;
  const float4* __restrict__ Wg = (const float4*)W;

  const float* xr = x + row * N_WIRES + lane * 8;
  float4 x0 = *(const float4*)(xr);
  float4 x1 = *(const float4*)(xr + 4);
  float v[8] = {x0.x, x0.y, x0.z, x0.w, x1.x, x1.y, x1.z, x1.w};

  // Register ring: PF pairs x 4 float4 = 96 VGPRs.
  float4 R[PF][4];
#pragma unroll
  for (int s = 0; s < PF; ++s) {
    const float4* p = Wg + s * 256 + lane;
    R[s][0] = p[0];
    R[s][1] = p[64];
    R[s][2] = p[128];
    R[s][3] = p[192];
  }

  for (int blk = 0; blk < (PAIRS / PF) - 1; ++blk) {   // 84 iterations
#pragma unroll
    for (int s = 0; s < PF; ++s) {
      // Retire exactly pair (blk*PF+s): 24 table loads outstanding -> 20.
      // Memory clobber pins every load on its side of this barrier.
      asm volatile("s_waitcnt vmcnt(20)" ::: "memory");
      even_layer(v, R[s][0], R[s][1]);
      odd_layer(v, R[s][2], R[s][3], lane);
      const float4* p = Wg + (blk * PF + s + PF) * 256 + lane;
      R[s][0] = p[0];
      R[s][1] = p[64];
      R[s][2] = p[128];
      R[s][3] = p[192];
    }
  }

  // Epilogue: pairs 504..509 already in the ring; one full drain (~200 cyc).
  asm volatile("s_waitcnt vmcnt(0)" ::: "memory");
#pragma unroll
  for (int s = 0; s < PF; ++s) {
    even_layer(v, R[s][0], R[s][1]);
    odd_layer(v, R[s][2], R[s][3], lane);
  }

  // Final even layer t = 1020 (block p=510, q0/q1; pre-masked identity).
  float4 f0 = Wg[FINAL4 + lane];
  float4 f1 = Wg[FINAL4 + 64 + lane];
  even_layer(v, f0, f1);

  const float* br = bias + lane * 8;
  float4 b0 = *(const float4*)(br);
  float4 b1 = *(const float4*)(br + 4);
  float4 o0 = {v[0] + b0.x, v[1] + b0.y, v[2] + b0.z, v[3] + b0.w};
  float4 o1 = {v[4] + b1.x, v[5] + b1.y, v[6] + b1.z, v[7] + b1.w};
  float* orow = out + row * N_WIRES + lane * 8;
  *(float4*)(orow) = o0;
  *(float4*)(orow + 4) = o1;
}

extern "C" void kernel_launch(void* const* d_in, const int* in_sizes, int n_in,
                              void* d_out, int out_size, void* d_ws,
                              size_t ws_size, hipStream_t stream) {
  const float* x = (const float*)d_in[0];       // (256, 512) f32
  const float* thetas = (const float*)d_in[1];  // (130816,) f32
  const float* bias = (const float*)d_in[2];    // (512,) f32
  float* out = (float*)d_out;                   // (256, 512) f32

  float* W = (float*)d_ws;                      // 130688 float4 = 2.09 MB

  sincos_kernel<<<(TOTAL2 + 255) / 256, 256, 0, stream>>>(thetas, (float2*)W);
  circuit_kernel<<<BATCH, 64, 0, stream>>>(x, W, bias, out);
}

// Round 7
// 114.907 us; speedup vs baseline: 1.3189x; 1.1641x over previous
//
#include <hip/hip_runtime.h>
#include <stdint.h>

// OrthogonalLinear: pyramid Givens circuit, n = m = 512, B = 256.
// T = 1021 layers; layer t has gates (i, i+1) for i = (t&1), (t&1)+2, ...,
// i <= min(t, 1020-t). theta index: k = (t+i)/2 + 1, idx = k(k-1)/2 + (k-1-i).
//
// Table W4 (d_ws), float4 units: pair p (layers t=2p, 2p+1) at [p*256,(p+1)*256).
// Quarter q in 0..3, lane L: idx = p*256 + q*64 + L:
//   q0 = (cE0,sE0,cE1,sE1)   even gates at wires 8L+0, 8L+2
//   q1 = (cE2,sE2,cE3,sE3)   even gates at wires 8L+4, 8L+6
//   q2 = (cO0,sO0,cO1,sO1)   odd  gates at wires 8L+1, 8L+3
//   q3 = (cO2,sO2,cU-1,sU)   odd gate at 8L+5; boundary gate (8L+7) stored
//                            as (c-1, s) so DPP's shifted-in 0 = identity.
// Block p=510 (128 float4, q=0/1, plain (c,s)) = final even layer t=1020.
// Total 130688 float4 = 2.09 MB. SC scratch (cos,sin per theta) after it.

#define N_WIRES 512
#define BATCH   256
#define PAIRS   510
#define PF      10                 // ring depth; 510 = 10 * 51
#define FINAL4  (PAIRS * 256)      // 130560
#define TOTAL4  (FINAL4 + 128)     // 130688
#define TOTAL2  (TOTAL4 * 2)       // 261376 float2 slots
#define N_THETAS 130816

// ---------------- kernel 1a: sincos once per theta ----------------
__global__ __launch_bounds__(256) void sc_kernel(
    const float* __restrict__ thetas, float2* __restrict__ SC) {
  int tid = blockIdx.x * 256 + threadIdx.x;
  if (tid >= N_THETAS) return;
  float c, s;
  __sincosf(thetas[tid], &s, &c);
  SC[tid] = make_float2(c, s);
}

// ---------------- kernel 1b: table build (no transcendentals) --------------
__global__ __launch_bounds__(256) void build_kernel(
    const float2* __restrict__ SC, float2* __restrict__ W2) {
  int tid = blockIdx.x * 256 + threadIdx.x;
  if (tid >= TOTAL2) return;
  int p = tid >> 9, r = tid & 511;
  int q = r >> 7, L = (r >> 1) & 63, e = r & 1, h = q >> 1;
  int t = 2 * p + h;
  int i = 8 * L + 4 * (q & 1) + 2 * e + h;
  float c = 1.0f, s = 0.0f;
  if (i <= min(t, 1020 - t)) {
    int k = ((t + i) >> 1) + 1;
    int idx = ((k * (k - 1)) >> 1) + (k - 1 - i);
    float2 cs = SC[idx];
    c = cs.x; s = cs.y;
  }
  if (q == 3 && e == 1) c -= 1.0f;   // boundary gate stored as (c-1, s)
  W2[tid] = make_float2(c, s);
}

// Fallback (ws too small for SC): fused sincos table build.
__global__ __launch_bounds__(256) void fused_kernel(
    const float* __restrict__ thetas, float2* __restrict__ W2) {
  int tid = blockIdx.x * 256 + threadIdx.x;
  if (tid >= TOTAL2) return;
  int p = tid >> 9, r = tid & 511;
  int q = r >> 7, L = (r >> 1) & 63, e = r & 1, h = q >> 1;
  int t = 2 * p + h;
  int i = 8 * L + 4 * (q & 1) + 2 * e + h;
  float c = 1.0f, s = 0.0f;
  if (i <= min(t, 1020 - t)) {
    int k = ((t + i) >> 1) + 1;
    int idx = ((k * (k - 1)) >> 1) + (k - 1 - i);
    __sincosf(thetas[idx], &s, &c);
  }
  if (q == 3 && e == 1) c -= 1.0f;
  W2[tid] = make_float2(c, s);
}

// ---------------- kernel 2: apply circuit, wave per row ----------------
template <int N>
__device__ __forceinline__ void wait_vm() {
  asm volatile("s_waitcnt vmcnt(%0)" ::"i"(N) : "memory");
}

__device__ __forceinline__ float dpp_shr1(float v) {  // lane i <- i-1; lane0 <- 0
  return __int_as_float(
      __builtin_amdgcn_mov_dpp(__float_as_int(v), 0x138, 0xF, 0xF, true));
}
__device__ __forceinline__ float dpp_shl1(float v) {  // lane i <- i+1; lane63 <- 0
  return __int_as_float(
      __builtin_amdgcn_mov_dpp(__float_as_int(v), 0x130, 0xF, 0xF, true));
}

// Packed Givens gate: P=(a,b), cs=(c,s) -> (c*a+s*b, c*b-s*a), 2 VOP3P instr.
__device__ __forceinline__ float2 gate_pk(float2 cs, float2 ab) {
  float2 t, r;
  asm("v_pk_mul_f32 %0, %1, %2 op_sel:[1,1] op_sel_hi:[1,0] neg_hi:[1,0]"
      : "=v"(t)
      : "v"(cs), "v"(ab));
  asm("v_pk_fma_f32 %0, %1, %2, %3 op_sel:[0,0,0] op_sel_hi:[0,1,1]"
      : "=v"(r)
      : "v"(cs), "v"(ab), "v"(t));
  return r;
}

__device__ __forceinline__ void gate_s(float& a, float& b, float c, float s) {
  float na = fmaf(c, a, s * b);
  float nb = fmaf(c, b, -(s * a));
  a = na;
  b = nb;
}

__device__ __forceinline__ void pair_compute(float2& A, float2& B, float2& C,
                                             float2& D, const float4& q0,
                                             const float4& q1, const float4& q2,
                                             const float4& q3) {
  // even layer: 4 packed gates
  A = gate_pk(make_float2(q0.x, q0.y), A);
  B = gate_pk(make_float2(q0.z, q0.w), B);
  C = gate_pk(make_float2(q1.x, q1.y), C);
  D = gate_pk(make_float2(q1.z, q1.w), D);
  // odd layer
  float cl_m1 = dpp_shr1(q3.z);   // left neighbor's (c-1); lane0 -> 0 = identity
  float sl    = dpp_shr1(q3.w);   // lane0 -> 0
  float rv0 = dpp_shl1(A.x);      // right neighbor's wire 8L+8 (post-even)
  float lv7 = dpp_shr1(D.y);      // left neighbor's wire 8L-1 (post-even)
  gate_s(A.y, B.x, q2.x, q2.y);
  gate_s(B.y, C.x, q2.z, q2.w);
  gate_s(C.y, D.x, q3.x, q3.y);
  // boundary: up-gate (8L+7, 8L+8) a-side, with c = 1 + q3.z:
  float nv7 = fmaf(q3.w, rv0, fmaf(q3.z, D.y, D.y));
  // down-gate (8L-1, 8L) b-side, c = 1 + cl_m1:
  float nv0 = fmaf(-sl, lv7, fmaf(cl_m1, A.x, A.x));
  D.y = nv7;
  A.x = nv0;
}

__global__ __launch_bounds__(64, 1) void circuit_kernel(
    const float* __restrict__ x, const float* __restrict__ W,
    const float* __restrict__ bias, float* __restrict__ out) {
  const int lane = threadIdx.x;
  const int row = blockIdx.x;
  const float4* __restrict__ Wg = (const float4*)W;

  const float* xr = x + row * N_WIRES + lane * 8;
  float4 x0 = *(const float4*)(xr);
  float4 x1 = *(const float4*)(xr + 4);

  // Register ring: PF pairs x 4 float4 = 160 VGPRs. Pointer induction.
  float4 R[PF][4];
  const float4* pw = Wg + lane;
#pragma unroll
  for (int s = 0; s < PF; ++s) {
    R[s][0] = pw[0];
    R[s][1] = pw[64];
    R[s][2] = pw[128];
    R[s][3] = pw[192];
    pw += 256;
  }

  // init state after issuing ring loads (keeps x-wait off the critical path)
  float2 A = make_float2(x0.x, x0.y), B = make_float2(x0.z, x0.w);
  float2 C = make_float2(x1.x, x1.y), D = make_float2(x1.z, x1.w);

  for (int blk = 0; blk < (PAIRS / PF) - 1; ++blk) {   // 50 iterations
#pragma unroll
    for (int s = 0; s < PF; ++s) {
      // outstanding = 40 table loads; retire exactly the oldest pair's 4.
      wait_vm<36>();
      pair_compute(A, B, C, D, R[s][0], R[s][1], R[s][2], R[s][3]);
      R[s][0] = pw[0];
      R[s][1] = pw[64];
      R[s][2] = pw[128];
      R[s][3] = pw[192];
      pw += 256;
    }
  }

  // Drain: pairs 500..509 already in ring (all loads issued); one full wait.
  wait_vm<0>();
#pragma unroll
  for (int s = 0; s < PF; ++s)
    pair_compute(A, B, C, D, R[s][0], R[s][1], R[s][2], R[s][3]);

  // Final even layer t = 1020 (block p=510, q0/q1, plain (c,s), pre-masked).
  float4 f0 = Wg[FINAL4 + lane];
  float4 f1 = Wg[FINAL4 + 64 + lane];
  A = gate_pk(make_float2(f0.x, f0.y), A);
  B = gate_pk(make_float2(f0.z, f0.w), B);
  C = gate_pk(make_float2(f1.x, f1.y), C);
  D = gate_pk(make_float2(f1.z, f1.w), D);

  const float* br = bias + lane * 8;
  float4 b0 = *(const float4*)(br);
  float4 b1 = *(const float4*)(br + 4);
  float4 o0 = {A.x + b0.x, A.y + b0.y, B.x + b0.z, B.y + b0.w};
  float4 o1 = {C.x + b1.x, C.y + b1.y, D.x + b1.z, D.y + b1.w};
  float* orow = out + row * N_WIRES + lane * 8;
  *(float4*)(orow) = o0;
  *(float4*)(orow + 4) = o1;
}

extern "C" void kernel_launch(void* const* d_in, const int* in_sizes, int n_in,
                              void* d_out, int out_size, void* d_ws,
                              size_t ws_size, hipStream_t stream) {
  const float* x = (const float*)d_in[0];       // (256, 512) f32
  const float* thetas = (const float*)d_in[1];  // (130816,) f32
  const float* bias = (const float*)d_in[2];    // (512,) f32
  float* out = (float*)d_out;                   // (256, 512) f32

  float* W = (float*)d_ws;                      // 130688 float4 = 2,091,008 B
  size_t table_bytes = (size_t)TOTAL4 * 16;
  size_t sc_bytes = (size_t)N_THETAS * 8;

  if (ws_size >= table_bytes + sc_bytes) {
    float2* SC = (float2*)((char*)d_ws + table_bytes);
    sc_kernel<<<(N_THETAS + 255) / 256, 256, 0, stream>>>(thetas, SC);
    build_kernel<<<(TOTAL2 + 255) / 256, 256, 0, stream>>>(SC, (float2*)W);
  } else {
    fused_kernel<<<(TOTAL2 + 255) / 256, 256, 0, stream>>>(thetas, (float2*)W);
  }
  circuit_kernel<<<BATCH, 64, 0, stream>>>(x, W, bias, out);
}